// Round 8
// baseline (128.996 us; speedup 1.0000x reference)
//
#include <hip/hip_runtime.h>

typedef _Float16 f16x8  __attribute__((ext_vector_type(8)));
typedef _Float16 f16x4  __attribute__((ext_vector_type(4)));
typedef _Float16 f16x2  __attribute__((ext_vector_type(2)));
typedef float    f32x4  __attribute__((ext_vector_type(4)));
typedef float    f32x16 __attribute__((ext_vector_type(16)));

#define MFMA32(a, b, c) __builtin_amdgcn_mfma_f32_32x32x16_f16((a), (b), (c), 0, 0, 0)

static constexpr int SEQ   = 2048;
static constexpr int DIM   = 128;
static constexpr int QBLK  = 128;          // 4 waves x 32 q-rows
static constexpr int KVBLK = 64;           // kv rows per tile (2 k-subtiles of 32)
static constexpr int NKT   = SEQ / KVBLK;  // 32
static constexpr int BH    = 2 * 16;
static constexpr int KSTR  = 136;          // K LDS row stride (f16), 272B padded
static constexpr int VSTR  = 72;           // Vt LDS row stride (f16), 144B padded

// o = exp(QK^T - rowmax) @ V  (unnormalized, fp32 in/out)
// 32x32x16 MFMA; Q pre-scaled by log2(e), softmax in exp2 domain.
// KVBLK=64: two independent QK accumulator chains (k 0-31 / 32-63);
// in-register softmax (q-col = lane&31, halves via shfl_xor 32);
// P exchanged with 2 shfl_xor per k-step; O^T = mfma(V^T, P^T).
__global__ __launch_bounds__(256, 2)
void fa_fwd_kernel(const float* __restrict__ Qg, const float* __restrict__ Kg,
                   const float* __restrict__ Vg, float* __restrict__ Og)
{
    __shared__ __align__(16) _Float16 Ksh[KVBLK * KSTR];   // 17408 B
    __shared__ __align__(16) _Float16 Vt[DIM * VSTR];      // 18432 B

    const int tid  = threadIdx.x;
    const int wv   = tid >> 6;
    const int lane = tid & 63;
    const int lq   = lane & 31;   // q column (and K/V A-row) owned by this lane
    const int lh   = lane >> 5;   // half: 0/1

    // XCD swizzle: all 16 q-tiles of one bh -> one XCD (K/V L2-resident)
    const int bi = blockIdx.x;
    const int bh = (bi & 7) + 8 * (bi >> 7);
    const int qt = (bi >> 3) & 15;

    const size_t base = (size_t)bh * SEQ * DIM;
    const float* Qp = Qg + base;
    const float* Kp = Kg + base;
    const float* Vp = Vg + base;
    float*       Op = Og + base;

    const int q0 = qt * QBLK + wv * 32;

    // ---- Q fragment (B-operand: col q = lq, elems d = 16t + 8*lh + j), x log2(e)
    constexpr float LOG2E = 1.44269504088896340736f;
    f16x8 qh[8];
    {
        const float* qs = Qp + (size_t)(q0 + lq) * DIM + 8 * lh;
#pragma unroll
        for (int t = 0; t < 8; ++t) {
            const float4 a = *(const float4*)(qs + 16 * t);
            const float4 b = *(const float4*)(qs + 16 * t + 4);
            float xs[8] = {a.x, a.y, a.z, a.w, b.x, b.y, b.z, b.w};
            f16x8 h;
#pragma unroll
            for (int e = 0; e < 8; ++e) h[e] = (_Float16)(xs[e] * LOG2E);
            qh[t] = h;
        }
    }

    // O^T accumulators: acc[dm][r] = O^T[d = 32*dm + (r&3)+8*(r>>2)+4*lh][q = lq]
    f32x16 acc[4];
#pragma unroll
    for (int a = 0; a < 4; ++a)
#pragma unroll
        for (int r = 0; r < 16; ++r) acc[a][r] = 0.0f;

    float mrow  = -3.0e38f;   // running (deferred) max, log2 units
    float mtrue = -3.0e38f;   // true running max, log2 units

    // staging maps (all static register indexing)
    const int ksr = tid >> 2, kc0 = (tid & 3) * 32;   // K: 4 threads/row, 32 floats
    const int vc  = tid & 31;                         // V: d cols {vc,vc+32,vc+64,vc+96}
    const int vk  = (tid >> 5) * 8;                   //    x 8 consecutive k rows
    const float* kb = Kp + (size_t)ksr * DIM + kc0;
    const float* vb = Vp + (size_t)vk * DIM + vc;

    float4 kreg[8];
    float  vreg[4][8];   // [d-col j][k-row r] — static indexing only
#pragma unroll
    for (int t = 0; t < 8; ++t) kreg[t] = *(const float4*)(kb + t * 4);
#pragma unroll
    for (int j = 0; j < 4; ++j)
#pragma unroll
        for (int r = 0; r < 8; ++r) vreg[j][r] = vb[(size_t)r * DIM + 32 * j];

    for (int kt = 0; kt < NKT; ++kt) {
        // ---- convert prefetched f32 regs to packed f16 (hides under prior compute)
        f16x8 kh16[4], vh16[4];
#pragma unroll
        for (int g = 0; g < 4; ++g) {
            float xs[8] = {kreg[2*g].x, kreg[2*g].y, kreg[2*g].z, kreg[2*g].w,
                           kreg[2*g+1].x, kreg[2*g+1].y, kreg[2*g+1].z, kreg[2*g+1].w};
            f16x8 h;
#pragma unroll
            for (int e = 0; e < 8; ++e) h[e] = (_Float16)xs[e];
            kh16[g] = h;
        }
#pragma unroll
        for (int j = 0; j < 4; ++j) {
            f16x8 h;
#pragma unroll
            for (int r = 0; r < 8; ++r) h[r] = (_Float16)vreg[j][r];
            vh16[j] = h;
        }

        __syncthreads();   // previous tile's LDS reads complete

        // ---- stage K (4 b128 writes) and V^T (4 b128 writes)
#pragma unroll
        for (int g = 0; g < 4; ++g)
            *(f16x8*)((char*)Ksh + (ksr * KSTR + kc0 + 8 * g) * 2) = kh16[g];
#pragma unroll
        for (int j = 0; j < 4; ++j) {
            const int d = vc + 32 * j;
            *(f16x8*)((char*)Vt + (d * VSTR + vk) * 2) = vh16[j];
        }
        __syncthreads();

        // ---- prefetch tile kt+1 (f32; converted at next loop top)
        if (kt + 1 < NKT) {
            const float* ks_ = kb + (size_t)(kt + 1) * KVBLK * DIM;
            const float* vs_ = vb + (size_t)(kt + 1) * KVBLK * DIM;
#pragma unroll
            for (int t = 0; t < 8; ++t) kreg[t] = *(const float4*)(ks_ + t * 4);
#pragma unroll
            for (int j = 0; j < 4; ++j)
#pragma unroll
                for (int r = 0; r < 8; ++r) vreg[j][r] = vs_[(size_t)r * DIM + 32 * j];
        }

        // ---- S^T = K Q^T: two independent chains (k 0-31 -> s0, k 32-63 -> s1)
        f32x16 s0, s1;
#pragma unroll
        for (int r = 0; r < 16; ++r) { s0[r] = 0.0f; s1[r] = 0.0f; }
        __builtin_amdgcn_s_setprio(1);
#pragma unroll
        for (int t = 0; t < 8; ++t) {
            f16x8 ka = *(const f16x8*)((const char*)Ksh + (lq * KSTR + 16 * t + 8 * lh) * 2);
            f16x8 kc = *(const f16x8*)((const char*)Ksh + ((lq + 32) * KSTR + 16 * t + 8 * lh) * 2);
            s0 = MFMA32(ka, qh[t], s0);
            s1 = MFMA32(kc, qh[t], s1);
        }
        __builtin_amdgcn_s_setprio(0);
        // s0[r] = S'^T[k = (r&3)+8*(r>>2)+4*lh][q=lq], s1: k + 32  (log2 units)

        // ---- online softmax over 64 k (halves l and l^32 share q-col lq)
        float tmax = fmaxf(s0[0], s1[0]);
#pragma unroll
        for (int r = 1; r < 16; ++r) tmax = fmaxf(tmax, fmaxf(s0[r], s1[r]));
        tmax = fmaxf(tmax, __shfl_xor(tmax, 32));
        mtrue = fmaxf(mtrue, tmax);

        // defer-max (T13): rescale only when some row grew by > THR (log2 units)
        if (!__all(tmax - mrow <= 10.0f)) {
            const float mn  = fmaxf(mrow, tmax);
            const float scl = __builtin_exp2f(mrow - mn);
            mrow = mn;
#pragma unroll
            for (int a = 0; a < 4; ++a)
#pragma unroll
                for (int r = 0; r < 16; ++r) acc[a][r] *= scl;
        }

        // ---- P^T packed f16 (bounded by 2^10; f16-safe)
        int pk[16];
#pragma unroll
        for (int i = 0; i < 8; ++i) {
            f16x2 e0 = {(_Float16)__builtin_exp2f(s0[2*i] - mrow),
                        (_Float16)__builtin_exp2f(s0[2*i+1] - mrow)};
            f16x2 e1 = {(_Float16)__builtin_exp2f(s1[2*i] - mrow),
                        (_Float16)__builtin_exp2f(s1[2*i+1] - mrow)};
            pk[i]     = __builtin_bit_cast(int, e0);
            pk[8 + i] = __builtin_bit_cast(int, e1);
        }

        // ---- PV: O^T += V^T P^T over 4 k-steps (k = 16s + 8lh + j)
#pragma unroll
        for (int s = 0; s < 4; ++s) {
            const int b  = (s >> 1) * 8;   // st0 for s<2, st1 for s>=2
            const int sl = s & 1;
            const int z1 = __shfl_xor(lh ? pk[b+4*sl+0] : pk[b+4*sl+2], 32);
            const int z2 = __shfl_xor(lh ? pk[b+4*sl+1] : pk[b+4*sl+3], 32);
            union { int i[4]; f16x8 v; } u;
            u.i[0] = lh ? z1 : pk[b+4*sl+0];
            u.i[1] = lh ? z2 : pk[b+4*sl+1];
            u.i[2] = lh ? pk[b+4*sl+2] : z1;
            u.i[3] = lh ? pk[b+4*sl+3] : z2;
            const f16x8 pb = u.v;
            __builtin_amdgcn_s_setprio(1);
#pragma unroll
            for (int dm = 0; dm < 4; ++dm) {
                const int d = dm * 32 + lq;
                f16x8 va = *(const f16x8*)((const char*)Vt + (d * VSTR + 16 * s + 8 * lh) * 2);
                acc[dm] = MFMA32(va, pb, acc[dm]);
            }
            __builtin_amdgcn_s_setprio(0);
        }
    }

    // ---- final correction to the true global row max (reference is unnormalized)
    const float fin = __builtin_exp2f(mrow - mtrue);
#pragma unroll
    for (int a = 0; a < 4; ++a)
#pragma unroll
        for (int r = 0; r < 16; ++r) acc[a][r] *= fin;

    // ---- store O: reg r of acc[dm] -> col d = 32*dm + 8*(r>>2) + 4*lh + (r&3)
    float* ob = Op + (size_t)(q0 + lq) * DIM + 4 * lh;
#pragma unroll
    for (int dm = 0; dm < 4; ++dm)
#pragma unroll
        for (int kp = 0; kp < 4; ++kp) {
            f32x4 v4 = {acc[dm][4*kp], acc[dm][4*kp+1], acc[dm][4*kp+2], acc[dm][4*kp+3]};
            *(f32x4*)(ob + dm * 32 + kp * 8) = v4;
        }
}

extern "C" void kernel_launch(void* const* d_in, const int* in_sizes, int n_in,
                              void* d_out, int out_size, void* d_ws, size_t ws_size,
                              hipStream_t stream) {
    const float* q = (const float*)d_in[0];
    const float* k = (const float*)d_in[1];
    const float* v = (const float*)d_in[2];
    float* o = (float*)d_out;
    dim3 grid((SEQ / QBLK) * BH);   // 512 blocks = 2/CU exact, XCD-swizzled in-kernel
    fa_fwd_kernel<<<grid, dim3(256), 0, stream>>>(q, k, v, o);
}